// Round 1
// baseline (525.299 us; speedup 1.0000x reference)
//
#include <hip/hip_runtime.h>
#include <math.h>

#define NB 32
#define SLEN 8192
#define DIM 64
#define M 64       // landmarks
#define SEG 128    // SLEN/M
#define SPLITS 32
#define CHUNK 256  // SLEN/SPLITS

// ws layout (float offsets):
//  ql_s   [NB][M][DIM]            @ 0        (q_land * 1/sqrt(D))
//  kl     [NB][M][DIM]            @ 131072
//  k2inv  [NB][M][M]              @ 262144
//  Wm     [NB][M][DIM]            @ 393216
//  k3     [NB][M][DIM]            @ 524288
//  den_p  [NB][SPLITS][M]         @ 655360
//  num_p  [NB][SPLITS][M][DIM]    @ 720896   (ends 4915200 floats = 19.7 MB)

// ---------------------------------------------------------------- pooling
__global__ __launch_bounds__(128) void pool_kernel(
    const float* __restrict__ q, const float* __restrict__ k,
    float* __restrict__ ql_s, float* __restrict__ kl) {
  int blk = blockIdx.x;            // b*64 + n
  int b = blk >> 6, n = blk & 63;
  int tid = threadIdx.x;
  int d = tid & 63, half = tid >> 6;
  const float* qb = q + (((size_t)b * SLEN) + (size_t)n * SEG) * DIM;
  const float* kb = k + (((size_t)b * SLEN) + (size_t)n * SEG) * DIM;
  float sq = 0.f, sk = 0.f;
  #pragma unroll 4
  for (int j = 0; j < 64; ++j) {
    int r = 2 * j + half;
    sq += qb[r * DIM + d];
    sk += kb[r * DIM + d];
  }
  __shared__ float red[2][64];
  if (half) { red[0][d] = sq; red[1][d] = sk; }
  __syncthreads();
  if (!half) {
    sq += red[0][d]; sk += red[1][d];
    size_t o = ((size_t)b * M + n) * DIM + d;
    ql_s[o] = sq * (1.f / 128.f) * 0.125f;   // mean, then *1/sqrt(64)
    kl[o]   = sk * (1.f / 128.f);
  }
}

// ------------------------------------------------- shared 64x64 matmul core
// A,B are [64][68]-padded row-major in LDS; 256 threads; each thread owns a
// 4x4 tile: rows m0..m0+3, cols n0..n0+3.
__device__ inline void mm_core(const float* __restrict__ Ab,
                               const float* __restrict__ Bb,
                               float (&c)[4][4]) {
  int tid = threadIdx.x;
  int m0 = (tid >> 4) << 2;
  int n0 = (tid & 15) << 2;
  #pragma unroll
  for (int i = 0; i < 4; ++i)
    #pragma unroll
    for (int j = 0; j < 4; ++j) c[i][j] = 0.f;
  #pragma unroll 4
  for (int kk = 0; kk < 64; kk += 4) {
    float4 a0 = *(const float4*)(Ab + (m0 + 0) * 68 + kk);
    float4 a1 = *(const float4*)(Ab + (m0 + 1) * 68 + kk);
    float4 a2 = *(const float4*)(Ab + (m0 + 2) * 68 + kk);
    float4 a3 = *(const float4*)(Ab + (m0 + 3) * 68 + kk);
    float4 b0 = *(const float4*)(Bb + (kk + 0) * 68 + n0);
    float4 b1 = *(const float4*)(Bb + (kk + 1) * 68 + n0);
    float4 b2 = *(const float4*)(Bb + (kk + 2) * 68 + n0);
    float4 b3 = *(const float4*)(Bb + (kk + 3) * 68 + n0);
#define MM_ROW(ci, av)                                                                     \
    ci[0] = fmaf(av.x, b0.x, ci[0]); ci[1] = fmaf(av.x, b0.y, ci[1]);                      \
    ci[2] = fmaf(av.x, b0.z, ci[2]); ci[3] = fmaf(av.x, b0.w, ci[3]);                      \
    ci[0] = fmaf(av.y, b1.x, ci[0]); ci[1] = fmaf(av.y, b1.y, ci[1]);                      \
    ci[2] = fmaf(av.y, b1.z, ci[2]); ci[3] = fmaf(av.y, b1.w, ci[3]);                      \
    ci[0] = fmaf(av.z, b2.x, ci[0]); ci[1] = fmaf(av.z, b2.y, ci[1]);                      \
    ci[2] = fmaf(av.z, b2.z, ci[2]); ci[3] = fmaf(av.z, b2.w, ci[3]);                      \
    ci[0] = fmaf(av.w, b3.x, ci[0]); ci[1] = fmaf(av.w, b3.y, ci[1]);                      \
    ci[2] = fmaf(av.w, b3.z, ci[2]); ci[3] = fmaf(av.w, b3.w, ci[3]);
    MM_ROW(c[0], a0)
    MM_ROW(c[1], a1)
    MM_ROW(c[2], a2)
    MM_ROW(c[3], a3)
#undef MM_ROW
  }
}

__device__ inline void mm64_lds(float* __restrict__ Cb, const float* __restrict__ Ab,
                                const float* __restrict__ Bb, float alpha) {
  float c[4][4];
  mm_core(Ab, Bb, c);
  int tid = threadIdx.x;
  int m0 = (tid >> 4) << 2, n0 = (tid & 15) << 2;
  #pragma unroll
  for (int i = 0; i < 4; ++i) {
    *(float4*)(Cb + (m0 + i) * 68 + n0) =
        make_float4(alpha * c[i][0], alpha * c[i][1], alpha * c[i][2], alpha * c[i][3]);
  }
}

// T = cdiag*I - U  (both [64][68] padded)
__device__ inline void ew_cimu(float* __restrict__ Tb, const float* __restrict__ Ub,
                               float cdiag) {
  int tid = threadIdx.x;
  #pragma unroll
  for (int e = 0; e < 16; ++e) {
    int idx = tid + 256 * e;          // 0..4095
    int m = idx >> 6, n = idx & 63;
    Tb[m * 68 + n] = (m == n ? cdiag : 0.f) - Ub[m * 68 + n];
  }
}

// dot(q_land_row, k_row) -> exp
__device__ inline float score_exp(const float* __restrict__ qlrow, const float (&kr)[64]) {
  const float4* q4 = (const float4*)qlrow;
  float4 acc = make_float4(0.f, 0.f, 0.f, 0.f);
  #pragma unroll
  for (int i = 0; i < 16; ++i) {
    float4 x = q4[i];
    acc.x = fmaf(x.x, kr[4 * i + 0], acc.x);
    acc.y = fmaf(x.y, kr[4 * i + 1], acc.y);
    acc.z = fmaf(x.z, kr[4 * i + 2], acc.z);
    acc.w = fmaf(x.w, kr[4 * i + 3], acc.w);
  }
  return __expf((acc.x + acc.y) + (acc.z + acc.w));
}

// --------------------------------------------- phase B partials + pinv blocks
__global__ __launch_bounds__(256) void phaseB_pinv_kernel(
    const float* __restrict__ k, const float* __restrict__ v,
    const float* __restrict__ ql_s, const float* __restrict__ klg,
    float* __restrict__ num_p, float* __restrict__ den_p, float* __restrict__ k2inv) {
  __shared__ float smem[21888];   // 87.5 KB, aliased by both roles
  int tid = threadIdx.x;

  if (blockIdx.x >= NB) {
    // ---------------- phase B: kernel_3 split partials ----------------
    int blk = blockIdx.x - NB;
    int b = blk >> 5, sp = blk & 31;
    float* ql  = smem;                 // [64][64] unpadded (broadcast reads)
    float* E   = smem + 4096;          // [256][68]
    float* dred = smem + 4096 + 256 * 68;  // [4][64]

    // stage ql (issue before k-row loads so both overlap)
    {
      const float4* src = (const float4*)(ql_s + (size_t)b * 4096);
      float4* dst = (float4*)ql;
      #pragma unroll
      for (int i = 0; i < 4; ++i) dst[tid + 256 * i] = src[tid + 256 * i];
    }
    // per-thread k row (independent of LDS)
    const float4* kr4 = (const float4*)(k + ((size_t)b * SLEN + (size_t)sp * CHUNK + tid) * DIM);
    float kr[64];
    #pragma unroll
    for (int i = 0; i < 16; ++i) {
      float4 t = kr4[i];
      kr[4 * i] = t.x; kr[4 * i + 1] = t.y; kr[4 * i + 2] = t.z; kr[4 * i + 3] = t.w;
    }
    __syncthreads();

    // scores + exp -> E[tid][m]
    for (int m = 0; m < 64; m += 4) {
      float4 ev;
      ev.x = score_exp(ql + (size_t)(m + 0) * 64, kr);
      ev.y = score_exp(ql + (size_t)(m + 1) * 64, kr);
      ev.z = score_exp(ql + (size_t)(m + 2) * 64, kr);
      ev.w = score_exp(ql + (size_t)(m + 3) * 64, kr);
      *(float4*)(E + (size_t)tid * 68 + m) = ev;
    }
    __syncthreads();

    // denominator partials
    {
      int m = tid & 63, qtr = tid >> 6;
      float ds = 0.f;
      #pragma unroll 8
      for (int s2 = 0; s2 < 64; ++s2) ds += E[(size_t)(qtr * 64 + s2) * 68 + m];
      dred[qtr * 64 + m] = ds;
    }
    __syncthreads();
    if (tid < 64) {
      float dn = dred[tid] + dred[64 + tid] + dred[128 + tid] + dred[192 + tid];
      den_p[((size_t)b * SPLITS + sp) * 64 + tid] = dn;
    }

    // num partial: num[m][d] = sum_s E[s][m] * v[s][d]
    int m0 = (tid >> 4) << 2, d0 = (tid & 15) << 2;
    const float4* vb = (const float4*)(v + ((size_t)b * SLEN + (size_t)sp * CHUNK) * DIM);
    float c[4][4];
    #pragma unroll
    for (int i = 0; i < 4; ++i)
      #pragma unroll
      for (int j = 0; j < 4; ++j) c[i][j] = 0.f;
    for (int s2 = 0; s2 < CHUNK; ++s2) {
      float4 e = *(const float4*)(E + (size_t)s2 * 68 + m0);
      float4 vv = vb[(size_t)s2 * 16 + (d0 >> 2)];
#define PB_ROW(ci, sc)                                                     \
      ci[0] = fmaf(sc, vv.x, ci[0]); ci[1] = fmaf(sc, vv.y, ci[1]);        \
      ci[2] = fmaf(sc, vv.z, ci[2]); ci[3] = fmaf(sc, vv.w, ci[3]);
      PB_ROW(c[0], e.x)
      PB_ROW(c[1], e.y)
      PB_ROW(c[2], e.z)
      PB_ROW(c[3], e.w)
#undef PB_ROW
    }
    float* np = num_p + ((size_t)b * SPLITS + sp) * 4096;
    #pragma unroll
    for (int i = 0; i < 4; ++i)
      *(float4*)(np + (size_t)(m0 + i) * 64 + d0) =
          make_float4(c[i][0], c[i][1], c[i][2], c[i][3]);
  } else {
    // ---------------- pinv: kernel_2 + Newton-Schulz ----------------
    int b = blockIdx.x;                 // 0..31
    float* K  = smem;                   // all [64][68]
    float* V  = smem + 4352;
    float* KV = smem + 8704;
    float* T  = smem + 13056;
    float* U  = smem + 17408;
    float* red = smem + 21760;

    // stage ql -> KV, kl -> T
    for (int e = tid; e < 4096; e += 256) {
      int m = e >> 6, dd = e & 63;
      KV[m * 68 + dd] = ql_s[(size_t)b * 4096 + e];
      T [m * 68 + dd] = klg [(size_t)b * 4096 + e];
    }
    __syncthreads();

    // kernel_2 = row-softmax(KV @ T^T) -> K  (scores tiny: skip max-sub)
    {
      int m = tid >> 2, ng = tid & 3;
      float ebuf[16];
      float lsum = 0.f;
      #pragma unroll
      for (int j = 0; j < 16; ++j) {
        int n = ng * 16 + j;
        float4 acc = make_float4(0.f, 0.f, 0.f, 0.f);
        #pragma unroll
        for (int i = 0; i < 16; ++i) {
          float4 a  = *(const float4*)(KV + m * 68 + 4 * i);
          float4 bb = *(const float4*)(T  + n * 68 + 4 * i);
          acc.x = fmaf(a.x, bb.x, acc.x);
          acc.y = fmaf(a.y, bb.y, acc.y);
          acc.z = fmaf(a.z, bb.z, acc.z);
          acc.w = fmaf(a.w, bb.w, acc.w);
        }
        float e = __expf((acc.x + acc.y) + (acc.z + acc.w));
        ebuf[j] = e; lsum += e;
      }
      lsum += __shfl_xor(lsum, 1);
      lsum += __shfl_xor(lsum, 2);
      float inv = 1.f / lsum;
      #pragma unroll
      for (int j = 0; j < 16; ++j) K[m * 68 + ng * 16 + j] = ebuf[j] * inv;
    }
    __syncthreads();

    // init: V = (1/max_col_sum) * K^T
    if (tid < 64) {
      float cs = 0.f;
      #pragma unroll 8
      for (int m2 = 0; m2 < 64; ++m2) cs += K[m2 * 68 + tid];
      float mx = cs;
      #pragma unroll
      for (int off = 1; off < 64; off <<= 1) mx = fmaxf(mx, __shfl_xor(mx, off));
      if (tid == 0) red[0] = 1.f / mx;
    }
    __syncthreads();
    float iscale = red[0];
    for (int e = tid; e < 4096; e += 256) {
      int r = e >> 6, cidx = e & 63;
      V[r * 68 + cidx] = K[cidx * 68 + r] * iscale;
    }
    __syncthreads();

    // 6 Newton-Schulz iterations
    for (int it = 0; it < 6; ++it) {
      mm64_lds(KV, K, V, 1.f);   __syncthreads();
      ew_cimu(T, KV, 7.f);       __syncthreads();
      mm64_lds(U, KV, T, 1.f);   __syncthreads();
      ew_cimu(T, U, 15.f);       __syncthreads();
      mm64_lds(U, KV, T, 1.f);   __syncthreads();
      ew_cimu(T, U, 13.f);       __syncthreads();
      mm64_lds(U, V, T, 0.25f);  __syncthreads();
      float* tmp = V; V = U; U = tmp;
    }
    for (int e = tid; e < 4096; e += 256)
      k2inv[(size_t)b * 4096 + e] = V[(e >> 6) * 68 + (e & 63)];
  }
}

// ------------------------------------------------ reduce split partials -> k3
__global__ __launch_bounds__(256) void combine1_kernel(
    const float* __restrict__ num_p, const float* __restrict__ den_p,
    float* __restrict__ k3) {
  int b = blockIdx.x >> 3, slice = blockIdx.x & 7;
  int tid = threadIdx.x;
  int e0 = slice * 512 + tid * 2;
  float a0 = 0.f, a1 = 0.f;
  for (int sp = 0; sp < SPLITS; ++sp) {
    float2 t = *(const float2*)(num_p + ((size_t)b * SPLITS + sp) * 4096 + e0);
    a0 += t.x; a1 += t.y;
  }
  int m = e0 >> 6;
  float dsum = 0.f;
  for (int sp = 0; sp < SPLITS; ++sp)
    dsum += den_p[((size_t)b * SPLITS + sp) * 64 + m];
  float dinv = 1.f / dsum;
  *(float2*)(k3 + (size_t)b * 4096 + e0) = make_float2(a0 * dinv, a1 * dinv);
}

// ------------------------------------------------------ W = k2inv @ k3
__global__ __launch_bounds__(256) void combine2_kernel(
    const float* __restrict__ k2inv, const float* __restrict__ k3,
    float* __restrict__ Wm) {
  __shared__ float A[4352], B[4352];
  int b = blockIdx.x, tid = threadIdx.x;
  int e0 = tid * 16, m = tid >> 2, dd = (tid & 3) * 16;
  const float4* sA = (const float4*)(k2inv + (size_t)b * 4096 + e0);
  const float4* sB = (const float4*)(k3    + (size_t)b * 4096 + e0);
  #pragma unroll
  for (int i = 0; i < 4; ++i) {
    *(float4*)(A + m * 68 + dd + 4 * i) = sA[i];
    *(float4*)(B + m * 68 + dd + 4 * i) = sB[i];
  }
  __syncthreads();
  float c[4][4];
  mm_core(A, B, c);
  int m0 = (tid >> 4) << 2, n0 = (tid & 15) << 2;
  #pragma unroll
  for (int i = 0; i < 4; ++i)
    *(float4*)(Wm + (size_t)b * 4096 + (size_t)(m0 + i) * 64 + n0) =
        make_float4(c[i][0], c[i][1], c[i][2], c[i][3]);
}

// --------------------------- final: x = softmax(q*scale @ kl^T) @ W, fused
__global__ __launch_bounds__(256) void final_kernel(
    const float* __restrict__ q, const float* __restrict__ klg,
    const float* __restrict__ Wm, float* __restrict__ out) {
  __shared__ float kls[4096];
  __shared__ float ws[4096];
  int b = blockIdx.x >> 5, rb = blockIdx.x & 31;
  int tid = threadIdx.x;
  {
    const float4* s1 = (const float4*)(klg + (size_t)b * 4096);
    const float4* s2 = (const float4*)(Wm  + (size_t)b * 4096);
    float4* d1 = (float4*)kls; float4* d2 = (float4*)ws;
    #pragma unroll
    for (int i = 0; i < 4; ++i) {
      d1[tid + 256 * i] = s1[tid + 256 * i];
      d2[tid + 256 * i] = s2[tid + 256 * i];
    }
  }
  size_t row = (size_t)b * SLEN + (size_t)rb * 256 + tid;
  const float4* qr4 = (const float4*)(q + row * DIM);
  float qr[64];
  #pragma unroll
  for (int i = 0; i < 16; ++i) {
    float4 t = qr4[i];
    qr[4 * i]     = t.x * 0.125f;
    qr[4 * i + 1] = t.y * 0.125f;
    qr[4 * i + 2] = t.z * 0.125f;
    qr[4 * i + 3] = t.w * 0.125f;
  }
  __syncthreads();

  float4 o[16];
  #pragma unroll
  for (int i = 0; i < 16; ++i) o[i] = make_float4(0.f, 0.f, 0.f, 0.f);
  float den = 0.f;
  for (int m = 0; m < 64; ++m) {
    float pm = score_exp(kls + (size_t)m * 64, qr);
    den += pm;
    const float4* wm = (const float4*)(ws + (size_t)m * 64);
    #pragma unroll
    for (int i = 0; i < 16; ++i) {
      float4 w = wm[i];
      o[i].x = fmaf(pm, w.x, o[i].x);
      o[i].y = fmaf(pm, w.y, o[i].y);
      o[i].z = fmaf(pm, w.z, o[i].z);
      o[i].w = fmaf(pm, w.w, o[i].w);
    }
  }
  float inv = 1.f / den;
  float4* orow = (float4*)(out + row * DIM);
  #pragma unroll
  for (int i = 0; i < 16; ++i) {
    float4 t = o[i];
    orow[i] = make_float4(t.x * inv, t.y * inv, t.z * inv, t.w * inv);
  }
}

// ----------------------------------------------------------------- launcher
extern "C" void kernel_launch(void* const* d_in, const int* in_sizes, int n_in,
                              void* d_out, int out_size, void* d_ws, size_t ws_size,
                              hipStream_t stream) {
  (void)in_sizes; (void)n_in; (void)out_size; (void)ws_size;
  const float* q = (const float*)d_in[0];
  const float* k = (const float*)d_in[1];
  const float* v = (const float*)d_in[2];
  float* out = (float*)d_out;
  float* ws = (float*)d_ws;

  float* ql_s  = ws;
  float* kl    = ws + 131072;
  float* k2inv = ws + 262144;
  float* Wm    = ws + 393216;
  float* k3    = ws + 524288;
  float* den_p = ws + 655360;
  float* num_p = ws + 720896;

  pool_kernel<<<NB * 64, 128, 0, stream>>>(q, k, ql_s, kl);
  // pinv blocks are 0..31 so they dispatch first and overlap with phase B
  phaseB_pinv_kernel<<<NB + NB * SPLITS, 256, 0, stream>>>(
      k, v, ql_s, kl, num_p, den_p, k2inv);
  combine1_kernel<<<NB * 8, 256, 0, stream>>>(num_p, den_p, k3);
  combine2_kernel<<<NB, 256, 0, stream>>>(k2inv, k3, Wm);
  final_kernel<<<NB * 32, 256, 0, stream>>>(q, kl, Wm, out);
}

// Round 3
// 350.134 us; speedup vs baseline: 1.5003x; 1.5003x over previous
//
#include <hip/hip_runtime.h>
#include <math.h>

#define NB 32
#define SLEN 8192
#define DIM 64
#define M 64
#define SEG 128
#define SPLITS 32
#define CHUNK 256

// ws layout (float offsets):
//  ql_s   [NB][M][DIM]            @ 0        (q_land * 1/sqrt(D), i.e. *0.125)
//  kl     [NB][M][DIM]            @ 131072
//  k2inv  [NB][M][M]              @ 262144   (pinv output V)
//  Wm     [NB][M][DIM]            @ 393216   (pinv scratch K2, then combine2's W)
//  k3     [NB][M][DIM]            @ 524288
//  den_p  [NB][SPLITS][M]         @ 655360
//  num_p  [NB][SPLITS][M][DIM]    @ 720896   (ends 4915200 floats = 19.7 MB)

// 16 fma: c[i][j] += a_i * bv[j]
#define ACC16(ax0, ax1, ax2, ax3, bv)                                          \
  c[0][0] = fmaf(ax0, bv.x, c[0][0]); c[0][1] = fmaf(ax0, bv.y, c[0][1]);      \
  c[0][2] = fmaf(ax0, bv.z, c[0][2]); c[0][3] = fmaf(ax0, bv.w, c[0][3]);      \
  c[1][0] = fmaf(ax1, bv.x, c[1][0]); c[1][1] = fmaf(ax1, bv.y, c[1][1]);      \
  c[1][2] = fmaf(ax1, bv.z, c[1][2]); c[1][3] = fmaf(ax1, bv.w, c[1][3]);      \
  c[2][0] = fmaf(ax2, bv.x, c[2][0]); c[2][1] = fmaf(ax2, bv.y, c[2][1]);      \
  c[2][2] = fmaf(ax2, bv.z, c[2][2]); c[2][3] = fmaf(ax2, bv.w, c[2][3]);      \
  c[3][0] = fmaf(ax3, bv.x, c[3][0]); c[3][1] = fmaf(ax3, bv.y, c[3][1]);      \
  c[3][2] = fmaf(ax3, bv.z, c[3][2]); c[3][3] = fmaf(ax3, bv.w, c[3][3]);

// c[i][j] += A[r0+i][kk] * B[kk][n0+j], kk over 64. A rows stride lda, B stride ldb.
__device__ __forceinline__ void mm_p1(const float* A, int lda, const float* B,
                                      int ldb, int r0, int n0, float (&c)[4][4]) {
  #pragma unroll 4
  for (int kk = 0; kk < 64; kk += 4) {
    float4 a0 = *(const float4*)(A + (r0 + 0) * lda + kk);
    float4 a1 = *(const float4*)(A + (r0 + 1) * lda + kk);
    float4 a2 = *(const float4*)(A + (r0 + 2) * lda + kk);
    float4 a3 = *(const float4*)(A + (r0 + 3) * lda + kk);
    float4 b0 = *(const float4*)(B + (kk + 0) * ldb + n0);
    float4 b1 = *(const float4*)(B + (kk + 1) * ldb + n0);
    float4 b2 = *(const float4*)(B + (kk + 2) * ldb + n0);
    float4 b3 = *(const float4*)(B + (kk + 3) * ldb + n0);
    ACC16(a0.x, a1.x, a2.x, a3.x, b0)
    ACC16(a0.y, a1.y, a2.y, a3.y, b1)
    ACC16(a0.z, a1.z, a2.z, a3.z, b2)
    ACC16(a0.w, a1.w, a2.w, a3.w, b3)
  }
}

// same, but B element (kk,n) transformed to (cd*I - B): fused Newton-Schulz step
__device__ __forceinline__ void mm_p1_tf(const float* A, int lda, const float* B,
                                         int ldb, float cd, int r0, int n0,
                                         float (&c)[4][4]) {
  #pragma unroll 4
  for (int kk = 0; kk < 64; kk += 4) {
    float4 a0 = *(const float4*)(A + (r0 + 0) * lda + kk);
    float4 a1 = *(const float4*)(A + (r0 + 1) * lda + kk);
    float4 a2 = *(const float4*)(A + (r0 + 2) * lda + kk);
    float4 a3 = *(const float4*)(A + (r0 + 3) * lda + kk);
    #pragma unroll
    for (int t = 0; t < 4; ++t) {
      float4 bb = *(const float4*)(B + (kk + t) * ldb + n0);
      int r = kk + t;
      bb.x = ((r == n0 + 0) ? cd : 0.f) - bb.x;
      bb.y = ((r == n0 + 1) ? cd : 0.f) - bb.y;
      bb.z = ((r == n0 + 2) ? cd : 0.f) - bb.z;
      bb.w = ((r == n0 + 3) ? cd : 0.f) - bb.w;
      float av0 = (t == 0) ? a0.x : (t == 1) ? a0.y : (t == 2) ? a0.z : a0.w;
      float av1 = (t == 0) ? a1.x : (t == 1) ? a1.y : (t == 2) ? a1.z : a1.w;
      float av2 = (t == 0) ? a2.x : (t == 1) ? a2.y : (t == 2) ? a2.z : a2.w;
      float av3 = (t == 0) ? a3.x : (t == 1) ? a3.y : (t == 2) ? a3.z : a3.w;
      ACC16(av0, av1, av2, av3, bb)
    }
  }
}

// outer-product accumulate: c[i][j] += A[s][m0+i] * B[s][n0+j], s over 64
__device__ __forceinline__ void mm_p2(const float* A, int lda, const float* B,
                                      int ldb, int m0, int n0, float (&c)[4][4]) {
  #pragma unroll 4
  for (int s = 0; s < 64; ++s) {
    float4 e = *(const float4*)(A + s * lda + m0);
    float4 vv = *(const float4*)(B + s * ldb + n0);
    ACC16(e.x, e.y, e.z, e.w, vv)
  }
}

// ---------------------------------------------------------------- pooling
__global__ __launch_bounds__(256) void pool_kernel(
    const float* __restrict__ q, const float* __restrict__ k,
    float* __restrict__ ql_s, float* __restrict__ kl) {
  int b = blockIdx.x >> 6, n = blockIdx.x & 63;
  int tid = threadIdx.x;
  int rg = tid >> 4, d4 = tid & 15;
  const float* qb = q + ((size_t)b * SLEN + (size_t)n * SEG) * DIM;
  const float* kb = k + ((size_t)b * SLEN + (size_t)n * SEG) * DIM;
  float4 aq = make_float4(0.f, 0.f, 0.f, 0.f);
  float4 ak = make_float4(0.f, 0.f, 0.f, 0.f);
  #pragma unroll
  for (int j = 0; j < 8; ++j) {
    int r = rg * 8 + j;
    float4 t = *(const float4*)(qb + r * DIM + 4 * d4);
    aq.x += t.x; aq.y += t.y; aq.z += t.z; aq.w += t.w;
    float4 u = *(const float4*)(kb + r * DIM + 4 * d4);
    ak.x += u.x; ak.y += u.y; ak.z += u.z; ak.w += u.w;
  }
  __shared__ float4 sq[256], sk[256];
  sq[tid] = aq; sk[tid] = ak;
  __syncthreads();
  #pragma unroll
  for (int off = 128; off >= 16; off >>= 1) {
    if (tid < off) {
      float4 a = sq[tid], bb = sq[tid + off];
      sq[tid] = make_float4(a.x + bb.x, a.y + bb.y, a.z + bb.z, a.w + bb.w);
      float4 c2 = sk[tid], d2 = sk[tid + off];
      sk[tid] = make_float4(c2.x + d2.x, c2.y + d2.y, c2.z + d2.z, c2.w + d2.w);
    }
    __syncthreads();
  }
  if (tid < 16) {
    float4 a = sq[tid], bb = sk[tid];
    size_t o = ((size_t)b * M + n) * DIM + 4 * tid;
    const float qs = 0.125f / 128.f, ks = 1.f / 128.f;
    *(float4*)(ql_s + o) = make_float4(a.x * qs, a.y * qs, a.z * qs, a.w * qs);
    *(float4*)(kl + o) = make_float4(bb.x * ks, bb.y * ks, bb.z * ks, bb.w * ks);
  }
}

// ---------------- phase B (kernel_3 split partials) + pinv, shared 53 KB LDS
__global__ __launch_bounds__(256) void phaseB_pinv_kernel(
    const float* __restrict__ k, const float* __restrict__ v,
    const float* __restrict__ ql_s, const float* __restrict__ klg,
    float* num_p, float* den_p, float* k2inv_g, float* k2_g) {
  __shared__ float smem[13312];  // 53248 B -> 3 blocks/CU
  int tid = threadIdx.x;
  int r0 = (tid >> 4) << 2, c0 = (tid & 15) << 2;

  if (blockIdx.x >= NB) {
    // ---------------- phase B ----------------
    int blk = blockIdx.x - NB;
    int b = blk >> 5, sp = blk & 31;
    float* qlT = smem;            // [64 d][68 m]  (ql_s transposed)
    float* kv = smem + 4352;      // [64 s][68]    (k tile, then v tile)
    float* Es = smem + 8704;      // [64 s][68 m]
    float* dredF = smem + 13056;  // [4][64]

    #pragma unroll
    for (int i = 0; i < 16; ++i) {
      int e = tid + 256 * i;
      qlT[(e & 63) * 68 + (e >> 6)] = ql_s[(size_t)b * 4096 + e];
    }
    int m_den = tid & 63, qg = tid >> 6;
    float den_acc = 0.f;
    float cN[4][4];
    #pragma unroll
    for (int i = 0; i < 4; ++i)
      #pragma unroll
      for (int j = 0; j < 4; ++j) cN[i][j] = 0.f;

    const float* kbase = k + ((size_t)b * SLEN + (size_t)sp * CHUNK) * DIM;
    const float* vbase = v + ((size_t)b * SLEN + (size_t)sp * CHUNK) * DIM;

    for (int sc = 0; sc < 4; ++sc) {
      // stage 64 k rows -> kv
      #pragma unroll
      for (int i = 0; i < 4; ++i) {
        int idx = tid + 256 * i;
        int s = idx >> 4, j = idx & 15;
        *(float4*)(kv + s * 68 + 4 * j) =
            *(const float4*)(kbase + (size_t)(sc * 64 + s) * DIM + 4 * j);
      }
      __syncthreads();
      // score GEMM: E[s][m] = exp(k[s] . ql_s[m])
      float c[4][4];
      #pragma unroll
      for (int i = 0; i < 4; ++i)
        #pragma unroll
        for (int j = 0; j < 4; ++j) c[i][j] = 0.f;
      mm_p1(kv, 68, qlT, 68, r0, c0, c);
      #pragma unroll
      for (int i = 0; i < 4; ++i)
        #pragma unroll
        for (int j = 0; j < 4; ++j) c[i][j] = __expf(c[i][j]);
      __syncthreads();  // kv reads done
      // write Es; stage v tile over kv
      #pragma unroll
      for (int i = 0; i < 4; ++i)
        *(float4*)(Es + (r0 + i) * 68 + c0) =
            make_float4(c[i][0], c[i][1], c[i][2], c[i][3]);
      #pragma unroll
      for (int i = 0; i < 4; ++i) {
        int idx = tid + 256 * i;
        int s = idx >> 4, j = idx & 15;
        *(float4*)(kv + s * 68 + 4 * j) =
            *(const float4*)(vbase + (size_t)(sc * 64 + s) * DIM + 4 * j);
      }
      __syncthreads();
      // den partial + num outer product
      #pragma unroll
      for (int t = 0; t < 16; ++t) den_acc += Es[(qg * 16 + t) * 68 + m_den];
      mm_p2(Es, 68, kv, 68, r0, c0, cN);
      __syncthreads();  // Es/kv reads done before next overwrite
    }
    dredF[qg * 64 + m_den] = den_acc;
    __syncthreads();
    if (tid < 64)
      den_p[((size_t)b * SPLITS + sp) * 64 + tid] =
          dredF[tid] + dredF[64 + tid] + dredF[128 + tid] + dredF[192 + tid];
    float* np = num_p + ((size_t)b * SPLITS + sp) * 4096;
    #pragma unroll
    for (int i = 0; i < 4; ++i)
      *(float4*)(np + (size_t)(r0 + i) * 64 + c0) =
          make_float4(cN[i][0], cN[i][1], cN[i][2], cN[i][3]);
  } else {
    // ---------------- pinv (3 buffers; K2 kept in global) ----------------
    int b = blockIdx.x;
    float* b1 = smem;            // ql rows, then V
    float* b2 = smem + 4352;     // klT, then A1=K*V
    float* b3 = smem + 8704;     // rowsum partials, K2 copy, then NS temp
    float* red = smem + 13056;   // [64+]
    float* k2b = k2_g + (size_t)b * 4096;

    #pragma unroll
    for (int i = 0; i < 4; ++i) {
      int idx = tid + 256 * i;
      int s = idx >> 4, j = idx & 15;
      *(float4*)(b1 + s * 68 + 4 * j) =
          *(const float4*)(ql_s + (size_t)b * 4096 + (size_t)s * 64 + 4 * j);
    }
    #pragma unroll
    for (int i = 0; i < 16; ++i) {
      int e = tid + 256 * i;
      b2[(e & 63) * 68 + (e >> 6)] = klg[(size_t)b * 4096 + e];
    }
    __syncthreads();
    // kernel_2 scores
    float c[4][4];
    #pragma unroll
    for (int i = 0; i < 4; ++i)
      #pragma unroll
      for (int j = 0; j < 4; ++j) c[i][j] = 0.f;
    mm_p1(b1, 68, b2, 68, r0, c0, c);
    #pragma unroll
    for (int i = 0; i < 4; ++i) {
      float pr = 0.f;
      #pragma unroll
      for (int j = 0; j < 4; ++j) { c[i][j] = __expf(c[i][j]); pr += c[i][j]; }
      b3[(r0 + i) * 16 + (tid & 15)] = pr;
    }
    __syncthreads();
    if (tid < 64) {
      float rs = 0.f;
      #pragma unroll
      for (int g = 0; g < 16; ++g) rs += b3[tid * 16 + g];
      red[tid] = 1.f / rs;
    }
    __syncthreads();
    // normalize -> K2 (global + LDS b3)
    #pragma unroll
    for (int i = 0; i < 4; ++i) {
      float inv = red[r0 + i];
      #pragma unroll
      for (int j = 0; j < 4; ++j) c[i][j] *= inv;
      float4 val = make_float4(c[i][0], c[i][1], c[i][2], c[i][3]);
      *(float4*)(k2b + (size_t)(r0 + i) * 64 + c0) = val;
      *(float4*)(b3 + (r0 + i) * 68 + c0) = val;
    }
    __syncthreads();
    // init scale: 1/max_m colsum
    if (tid < 64) {
      float cs = 0.f;
      #pragma unroll 8
      for (int n2 = 0; n2 < 64; ++n2) cs += b3[n2 * 68 + tid];
      float mx = cs;
      #pragma unroll
      for (int off = 1; off < 64; off <<= 1) mx = fmaxf(mx, __shfl_xor(mx, off));
      red[0] = 1.f / mx;
    }
    __syncthreads();
    float iscale = red[0];
    // V = iscale * K2^T -> b1 (ql dead)
    #pragma unroll
    for (int i = 0; i < 16; ++i) {
      int e = tid + 256 * i;
      int r = e >> 6, cc = e & 63;
      b1[r * 68 + cc] = b3[cc * 68 + r] * iscale;
    }
    __syncthreads();

    for (int it = 0; it < 6; ++it) {
      // A1 = K2 @ V -> b2
      #pragma unroll
      for (int i = 0; i < 4; ++i)
        #pragma unroll
        for (int j = 0; j < 4; ++j) c[i][j] = 0.f;
      mm_p1(k2b, 64, b1, 68, r0, c0, c);
      #pragma unroll
      for (int i = 0; i < 4; ++i)
        *(float4*)(b2 + (r0 + i) * 68 + c0) =
            make_float4(c[i][0], c[i][1], c[i][2], c[i][3]);
      __syncthreads();
      // T = A1 @ (7I - A1) -> b3
      #pragma unroll
      for (int i = 0; i < 4; ++i)
        #pragma unroll
        for (int j = 0; j < 4; ++j) c[i][j] = 0.f;
      mm_p1_tf(b2, 68, b2, 68, 7.f, r0, c0, c);
      #pragma unroll
      for (int i = 0; i < 4; ++i)
        *(float4*)(b3 + (r0 + i) * 68 + c0) =
            make_float4(c[i][0], c[i][1], c[i][2], c[i][3]);
      __syncthreads();
      // R = A1 @ (15I - T) -> b3 in place (barrier before write)
      #pragma unroll
      for (int i = 0; i < 4; ++i)
        #pragma unroll
        for (int j = 0; j < 4; ++j) c[i][j] = 0.f;
      mm_p1_tf(b2, 68, b3, 68, 15.f, r0, c0, c);
      __syncthreads();
      #pragma unroll
      for (int i = 0; i < 4; ++i)
        *(float4*)(b3 + (r0 + i) * 68 + c0) =
            make_float4(c[i][0], c[i][1], c[i][2], c[i][3]);
      __syncthreads();
      // V = 0.25 * V @ (13I - R) -> b1 in place
      #pragma unroll
      for (int i = 0; i < 4; ++i)
        #pragma unroll
        for (int j = 0; j < 4; ++j) c[i][j] = 0.f;
      mm_p1_tf(b1, 68, b3, 68, 13.f, r0, c0, c);
      __syncthreads();
      #pragma unroll
      for (int i = 0; i < 4; ++i)
        *(float4*)(b1 + (r0 + i) * 68 + c0) = make_float4(
            0.25f * c[i][0], 0.25f * c[i][1], 0.25f * c[i][2], 0.25f * c[i][3]);
      __syncthreads();
    }
    #pragma unroll
    for (int i = 0; i < 16; ++i) {
      int e = tid + 256 * i;
      k2inv_g[(size_t)b * 4096 + e] = b1[(e >> 6) * 68 + (e & 63)];
    }
  }
}

// ------------------------------------------------ reduce split partials -> k3
__global__ __launch_bounds__(256) void combine1_kernel(
    const float* __restrict__ num_p, const float* __restrict__ den_p,
    float* __restrict__ k3) {
  int b = blockIdx.x >> 3, slice = blockIdx.x & 7;
  int tid = threadIdx.x;
  int e0 = slice * 512 + tid * 2;
  float a0 = 0.f, a1 = 0.f;
  for (int sp = 0; sp < SPLITS; ++sp) {
    float2 t = *(const float2*)(num_p + ((size_t)b * SPLITS + sp) * 4096 + e0);
    a0 += t.x; a1 += t.y;
  }
  int m = e0 >> 6;
  float dsum = 0.f;
  for (int sp = 0; sp < SPLITS; ++sp)
    dsum += den_p[((size_t)b * SPLITS + sp) * 64 + m];
  float dinv = 1.f / dsum;
  *(float2*)(k3 + (size_t)b * 4096 + e0) = make_float2(a0 * dinv, a1 * dinv);
}

// ------------------------------------------------------ W = k2inv @ k3
__global__ __launch_bounds__(256) void combine2_kernel(
    const float* __restrict__ k2inv, const float* __restrict__ k3,
    float* __restrict__ Wm) {
  __shared__ float A[4352], Bm[4352];
  int b = blockIdx.x, tid = threadIdx.x;
  int r0 = (tid >> 4) << 2, c0 = (tid & 15) << 2;
  #pragma unroll
  for (int i = 0; i < 4; ++i) {
    int idx = tid + 256 * i;
    int s = idx >> 4, j = idx & 15;
    *(float4*)(A + s * 68 + 4 * j) =
        *(const float4*)(k2inv + (size_t)b * 4096 + (size_t)s * 64 + 4 * j);
    *(float4*)(Bm + s * 68 + 4 * j) =
        *(const float4*)(k3 + (size_t)b * 4096 + (size_t)s * 64 + 4 * j);
  }
  __syncthreads();
  float c[4][4];
  #pragma unroll
  for (int i = 0; i < 4; ++i)
    #pragma unroll
    for (int j = 0; j < 4; ++j) c[i][j] = 0.f;
  mm_p1(A, 68, Bm, 68, r0, c0, c);
  #pragma unroll
  for (int i = 0; i < 4; ++i)
    *(float4*)(Wm + (size_t)b * 4096 + (size_t)(r0 + i) * 64 + c0) =
        make_float4(c[i][0], c[i][1], c[i][2], c[i][3]);
}

// --------------------------- final: x = softmax(q*scale @ kl^T) @ W, tiled
#define FROWS 128
__global__ __launch_bounds__(256) void final_kernel(
    const float* __restrict__ q, const float* __restrict__ klg,
    const float* __restrict__ Wm, float* __restrict__ out) {
  __shared__ float smem[13120];  // 52480 B -> 3 blocks/CU
  float* klT = smem;             // [64 d][68 m]
  float* Wl = smem + 4352;       // [64 m][64 d]
  float* Es = smem + 8448;       // q tile, then E tile [64 r][68]
  float* dred = smem + 12800;    // [4][64]
  float* denF = smem + 13056;    // [64]
  int b = blockIdx.x >> 6, rb = blockIdx.x & 63;
  int tid = threadIdx.x;
  int r0 = (tid >> 4) << 2, c0 = (tid & 15) << 2;
  int rr = tid & 63, qg = tid >> 6;

  #pragma unroll
  for (int i = 0; i < 16; ++i) {
    int e = tid + 256 * i;
    klT[(e & 63) * 68 + (e >> 6)] = klg[(size_t)b * 4096 + e];
  }
  #pragma unroll
  for (int i = 0; i < 4; ++i) {
    int idx = tid + 256 * i;
    *(float4*)(Wl + idx * 4) = *(const float4*)(Wm + (size_t)b * 4096 + idx * 4);
  }
  __syncthreads();

  for (int sc = 0; sc < FROWS / 64; ++sc) {
    const float* qsrc = q + ((size_t)b * SLEN + (size_t)rb * FROWS + sc * 64) * DIM;
    #pragma unroll
    for (int i = 0; i < 4; ++i) {
      int idx = tid + 256 * i;
      int s = idx >> 4, j = idx & 15;
      float4 t = *(const float4*)(qsrc + (size_t)s * DIM + 4 * j);
      *(float4*)(Es + s * 68 + 4 * j) =
          make_float4(t.x * 0.125f, t.y * 0.125f, t.z * 0.125f, t.w * 0.125f);
    }
    __syncthreads();
    float c[4][4];
    #pragma unroll
    for (int i = 0; i < 4; ++i)
      #pragma unroll
      for (int j = 0; j < 4; ++j) c[i][j] = 0.f;
    mm_p1(Es, 68, klT, 68, r0, c0, c);
    #pragma unroll
    for (int i = 0; i < 4; ++i)
      #pragma unroll
      for (int j = 0; j < 4; ++j) c[i][j] = __expf(c[i][j]);
    __syncthreads();  // q-tile reads done
    #pragma unroll
    for (int i = 0; i < 4; ++i)
      *(float4*)(Es + (r0 + i) * 68 + c0) =
          make_float4(c[i][0], c[i][1], c[i][2], c[i][3]);
    __syncthreads();
    // den[r] = sum_m E[r][m]
    float ds = 0.f;
    #pragma unroll
    for (int t = 0; t < 4; ++t) {
      float4 x = *(const float4*)(Es + rr * 68 + qg * 16 + 4 * t);
      ds += (x.x + x.y) + (x.z + x.w);
    }
    dred[qg * 64 + rr] = ds;
    __syncthreads();
    if (tid < 64)
      denF[tid] =
          1.f / (dred[tid] + dred[64 + tid] + dred[128 + tid] + dred[192 + tid]);
    __syncthreads();
    // out = (E @ W) * 1/den
    float c3[4][4];
    #pragma unroll
    for (int i = 0; i < 4; ++i)
      #pragma unroll
      for (int j = 0; j < 4; ++j) c3[i][j] = 0.f;
    mm_p1(Es, 68, Wl, 64, r0, c0, c3);
    float* orow = out + ((size_t)b * SLEN + (size_t)rb * FROWS + sc * 64) * DIM;
    #pragma unroll
    for (int i = 0; i < 4; ++i) {
      float inv = denF[r0 + i];
      *(float4*)(orow + (size_t)(r0 + i) * 64 + c0) = make_float4(
          c3[i][0] * inv, c3[i][1] * inv, c3[i][2] * inv, c3[i][3] * inv);
    }
    __syncthreads();  // Es reads done before next stage
  }
}

// ----------------------------------------------------------------- launcher
extern "C" void kernel_launch(void* const* d_in, const int* in_sizes, int n_in,
                              void* d_out, int out_size, void* d_ws, size_t ws_size,
                              hipStream_t stream) {
  (void)in_sizes; (void)n_in; (void)out_size; (void)ws_size;
  const float* q = (const float*)d_in[0];
  const float* k = (const float*)d_in[1];
  const float* v = (const float*)d_in[2];
  float* out = (float*)d_out;
  float* ws = (float*)d_ws;

  float* ql_s = ws;
  float* kl = ws + 131072;
  float* k2inv = ws + 262144;
  float* Wm = ws + 393216;  // pinv K2 scratch, then combine2 output
  float* k3 = ws + 524288;
  float* den_p = ws + 655360;
  float* num_p = ws + 720896;

  pool_kernel<<<NB * 64, 256, 0, stream>>>(q, k, ql_s, kl);
  phaseB_pinv_kernel<<<NB + NB * SPLITS, 256, 0, stream>>>(
      k, v, ql_s, kl, num_p, den_p, k2inv, Wm);
  combine1_kernel<<<NB * 8, 256, 0, stream>>>(num_p, den_p, k3);
  combine2_kernel<<<NB, 256, 0, stream>>>(k2inv, k3, Wm);
  final_kernel<<<NB * 64, 256, 0, stream>>>(q, kl, Wm, out);
}